// Round 13
// baseline (186.096 us; speedup 1.0000x reference)
//
#include <hip/hip_runtime.h>
#include <hip/hip_bf16.h>
#include <stdint.h>

// Correlation (FlowNet), md=4: out[b, di*9+dj, h, w] = sum_c x[b,c,h,w]*yp[b,c,h+di-4,w+dj-4] / 256
// R12 = R11 packed-pair formulation (acc 40 regs) + ONE mechanism change:
// loads for chunk t+1 are issued AFTER the write barrier and BEFORE compute(t),
// pinned by sched_barrier(0). Their vmcnt wait (at cvt of t+1) is then a full
// compute phase downstream -> HBM misses stay outstanding during compute
// (~100% miss-queue duty cycle vs ~50% for the R9/R11 burst-then-drain order).
// setprio dropped (lockstep structure; m190).

using f32x4 = __attribute__((ext_vector_type(4))) float;
using s16x4 = __attribute__((ext_vector_type(4))) short;
using u16x4 = __attribute__((ext_vector_type(4))) unsigned short;

#define C_DIM 256
#define H_DIM 96
#define W_DIM 192
#define HWSZ  (H_DIM * W_DIM)
#define MD 4
#define KD 9
#define CHUNK 32
#define NCHUNK 8
#define HR 8
#define NTHR 512
#define WTILES 12          // 192/16
#define HQ 12              // 96/8
#define YROW_B 2048        // 8 cg x (2 phasings x 128B) per y row (32c)
#define XBASE  (16 * YROW_B)            // 32768
#define LDS_BYTES (XBASE + 8 * 1024)    // + 8 (p,wh) A-units x 1024B = 40960
#define NSLOT 10           // per-thread staging slots: 8 y + 2 x

static __device__ __forceinline__ unsigned short bf16b(float f) {
  __bf16 h = (__bf16)f;                   // RNE
  unsigned short s; __builtin_memcpy(&s, &h, 2); return s;
}

// per-lane: reads column (addr&127)/8 of the 128B [4c][16m] bf16 subtile at addr
static __device__ __forceinline__ s16x4 tr16(uint32_t addr) {
  s16x4 d;
  asm volatile("ds_read_b64_tr_b16 %0, %1" : "=v"(d) : "v"(addr));
  return d;
}

#define WAITLG(n) asm volatile("s_waitcnt lgkmcnt(" #n ")" ::: "memory")

__global__ __launch_bounds__(NTHR, 4)
void corr_mfma(const float* __restrict__ xg, const float* __restrict__ yg,
               float* __restrict__ outg) {
  __shared__ __align__(16) char smem[LDS_BYTES];

  const int bid = blockIdx.x;             // 1152 = 8 * 144
  const int b   = bid & 7;                // batch == XCD (round-robin dispatch)
  const int rem = bid >> 3;               // hq fastest -> h-halo L2 reuse
  const int wt  = rem / HQ;
  const int hq  = rem - wt * HQ;
  const int w0  = wt * 16;
  const int h0  = hq * HR;

  const int tid  = threadIdx.x;
  const int lane = tid & 63;
  const int wv   = tid >> 6;              // 0..7
  const int p    = wv >> 1;               // h-pair: rows h0+2p, h0+2p+1
  const int wh   = wv & 1;                // w-half: w0+8*wh
  const int hi   = lane >> 4;
  const int lm   = lane & 15;

  const uint32_t sbase = (uint32_t)(uintptr_t)&smem[0];

  // ---- staging decode, hoisted: 5120 slots = 10/thread (8 y + 2 x).
  uint32_t goff[NSLOT], loff[NSLOT];
  uint32_t vmask = 0;
#pragma unroll
  for (int i = 0; i < NSLOT; ++i) {
    const int sid = i * NTHR + tid;
    if (i < 8) {                          // y slots (sid < 4096)
      const int r  = sid >> 8;            // 0..15 -> y row h0+r-4
      const int u  = sid & 255;
      const int c  = u >> 3;              // 0..31
      const int ph = (u >> 2) & 1;
      const int qp = u & 3;
      const int hg = h0 + r - MD;
      const int sg = w0 - MD + 8 * ph + 4 * qp;   // 4-aligned: OOB whole-quad
      const bool ok = (hg >= 0) && (hg < H_DIM) && (sg >= 0) && (sg + 3 < W_DIM);
      if (ok) vmask |= (1u << i);
      goff[i] = ok ? (uint32_t)(((b * C_DIM + c) * H_DIM + hg) * W_DIM + sg) : 0u;
      loff[i] = r * YROW_B + (c >> 2) * 256 + ph * 128 + (c & 3) * 32 + qp * 8;
    } else {                              // x slots
      const int v  = sid - 4096;          // 0..1023
      const int r8 = v >> 7;              // 0..7
      const int u  = v & 127;
      const int c  = u >> 2;
      const int q  = u & 3;               // w-quad: w0+4q
      vmask |= (1u << i);
      goff[i] = (uint32_t)(((b * C_DIM + c) * H_DIM + (h0 + r8)) * W_DIM + (w0 + 4 * q));
      loff[i] = XBASE + ((r8 >> 1) * 2 + (q >> 1)) * 1024 + (c >> 2) * 128
              + (c & 3) * 32 + ((r8 & 1) * 8 + (q & 1) * 4) * 2;
    }
  }

  f32x4 acc[10];
#pragma unroll
  for (int r = 0; r < 10; ++r) acc[r] = f32x4{0.f, 0.f, 0.f, 0.f};

  // A base: unit (p,wh), subtile cg = kh*4+hi (kh adds 512), col m = lm
  const uint32_t abase = sbase + XBASE + (uint32_t)(p * 2 + wh) * 1024 + hi * 128 + lm * 8;
  // B base: y LDS row (2p + r), cg at 256B (kh adds 1024), phasing wh
  const uint32_t bbase = sbase + (uint32_t)(2 * p) * YROW_B + hi * 256 + wh * 128 + lm * 8;

  // ---- prologue: issue chunk 0 loads (in flight through first cvt)
  float4 vv[NSLOT];
#pragma unroll
  for (int i = 0; i < NSLOT; ++i) {
    float4 v = make_float4(0.f, 0.f, 0.f, 0.f);
    if (vmask & (1u << i)) v = *(const float4*)((i < 8 ? yg : xg) + goff[i]);
    vv[i] = v;
  }

  for (int t = 0; t < NCHUNK; ++t) {
    // ---- cvt chunk t (vmcnt wait lands here: loads are one compute phase old)
    u16x4 wbuf[NSLOT];
#pragma unroll
    for (int i = 0; i < NSLOT; ++i)
      wbuf[i] = u16x4{bf16b(vv[i].x), bf16b(vv[i].y), bf16b(vv[i].z), bf16b(vv[i].w)};

    __syncthreads();                      // previous chunk's LDS reads done
#pragma unroll
    for (int i = 0; i < NSLOT; ++i) *(u16x4*)(smem + loff[i]) = wbuf[i];
    __syncthreads();

    // ---- issue chunk t+1 loads NOW (before compute), pinned by sched_barrier:
    // misses stay outstanding under the whole compute phase.
    if (t + 1 < NCHUNK) {
      const uint32_t co = (uint32_t)(t + 1) * CHUNK * HWSZ;
#pragma unroll
      for (int i = 0; i < NSLOT; ++i) {
        float4 v = make_float4(0.f, 0.f, 0.f, 0.f);
        if (vmask & (1u << i)) v = *(const float4*)((i < 8 ? yg : xg) + goff[i] + co);
        vv[i] = v;
      }
    }
    __builtin_amdgcn_sched_barrier(0);    // don't sink the loads into/past compute

    // ---- compute chunk t: A frags + 10 B-rows, 2-slot rotated, counted lgkm
    s16x4 afr0 = tr16(abase);
    s16x4 afr1 = tr16(abase + 512);
    s16x4 bsl[2][2];

#define ISSUE_R(r) { \
    const uint32_t ba = bbase + (uint32_t)(r) * YROW_B; \
    bsl[(r) & 1][0] = tr16(ba); \
    bsl[(r) & 1][1] = tr16(ba + 1024); }

#define DO_R(r, lg) \
    WAITLG(lg); __builtin_amdgcn_sched_barrier(0); \
    acc[r] = __builtin_amdgcn_mfma_f32_16x16x16bf16_1k(afr0, bsl[(r) & 1][0], acc[r], 0, 0, 0); \
    acc[r] = __builtin_amdgcn_mfma_f32_16x16x16bf16_1k(afr1, bsl[(r) & 1][1], acc[r], 0, 0, 0);

    ISSUE_R(0)
    ISSUE_R(1)
    DO_R(0, 2)
    ISSUE_R(2)
    DO_R(1, 2)
    ISSUE_R(3)
    DO_R(2, 2)
    ISSUE_R(4)
    DO_R(3, 2)
    ISSUE_R(5)
    DO_R(4, 2)
    ISSUE_R(6)
    DO_R(5, 2)
    ISSUE_R(7)
    DO_R(6, 2)
    ISSUE_R(8)
    DO_R(7, 2)
    ISSUE_R(9)
    DO_R(8, 2)
    DO_R(9, 0)
#undef ISSUE_R
#undef DO_R
  }

  // ---- epilogue: D[m][n]: m = hi*4+rg = (j<<3)|w, n = lm. di = r-j, dj = lm-w.
  const float scale = 1.f / 256.f;
#pragma unroll
  for (int r = 0; r < 10; ++r) {
#pragma unroll
    for (int rg = 0; rg < 4; ++rg) {
      const int m = hi * 4 + rg;
      const int j = m >> 3;
      const int w = m & 7;
      const int di = r - j;
      const int dj = lm - w;
      if (0 <= di && di < KD && 0 <= dj && dj < KD) {
        outg[((b * (KD * KD) + di * KD + dj) * H_DIM + (h0 + 2 * p + j)) * W_DIM
             + (w0 + 8 * wh + w)] = acc[r][rg] * scale;
      }
    }
  }
}

extern "C" void kernel_launch(void* const* d_in, const int* in_sizes, int n_in,
                              void* d_out, int out_size, void* d_ws, size_t ws_size,
                              hipStream_t stream) {
  const float* x = (const float*)d_in[0];
  const float* y = (const float*)d_in[1];
  float* out = (float*)d_out;
  (void)in_sizes; (void)n_in; (void)d_ws; (void)ws_size; (void)out_size;

  const int grid = 8 * HQ * WTILES;       // 1152 blocks, 512 threads
  corr_mfma<<<dim3(grid), dim3(NTHR), 0, stream>>>(x, y, out);
}